// Round 8
// baseline (158.772 us; speedup 1.0000x reference)
//
#include <hip/hip_runtime.h>

// Problem constants (from setup_inputs): B=4, N=100000, M=64
#define B_IMGS 4
#define N_PROP 100000
#define M_GT   64
#define REP    4   // R8 diagnostic: repeat body 4x (idempotent) so the kernel
                   // dispatch exceeds the ~42us fill kernels and shows up in
                   // the top-5 profile rows with real counters. dur_us ~= floor + 4*k.

// Output layout (flat f32): decoded[B*N*4] | targets[B*N*4] | matches[B*N]
//
// R8 change vs R7: NO LDS at all. gt areas are computed inline from the
// wave-uniform s_loaded box (same f32 op order as numpy -> bit-identical).
// Hot loop is pure {s_load + VALU}: no ds_read, no lgkm ds/smem mixing,
// no __syncthreads. IoU math unchanged (rcp hot loop + top-2 + 2e-6-margin
// exact-div fallback, first-max-wins).

__global__ __launch_bounds__(256) void roihead_kernel(
    const float* __restrict__ proposals,  // [B,N,4]
    const float* __restrict__ gt,         // [B,M,4]
    const float* __restrict__ deltas,     // [B,N,4]
    float* __restrict__ out)
{
    const int b = blockIdx.y;
    const int n = blockIdx.x * blockDim.x + threadIdx.x;
    if (n >= N_PROP) return;

    for (int r = 0; r < REP; ++r) {
        // Opaque pointer copies: defeats CSE/LICM across reps so each rep
        // re-executes the full computation; "+s" keeps them in SGPRs so the
        // wave-uniform gt loads still scalarize to s_load.
        const float* pprop = proposals;
        const float* pgt   = gt;
        const float* pdel  = deltas;
        float*       pout  = out;
        asm volatile("" : "+s"(pprop), "+s"(pgt), "+s"(pdel), "+s"(pout));

        const float4* __restrict__ gt4 =
            reinterpret_cast<const float4*>(pgt) + b * M_GT;

        const long pi = (long)b * N_PROP + n;
        const float4 p = reinterpret_cast<const float4*>(pprop)[pi];

        float bv1 = -1.0f, bv2 = -1.0f; int bi = 0;
        float ap;
        {
#pragma clang fp contract(off)
            ap = (p.z - p.x) * (p.w - p.y);
#pragma unroll 8
            for (int m = 0; m < M_GT; ++m) {
                const float4 g  = gt4[m];                    // wave-uniform s_load
                const float  ga = (g.z - g.x) * (g.w - g.y); // numpy op order
                const float wx = fmaxf(fminf(g.z, p.z) - fmaxf(g.x, p.x), 0.0f);
                const float wy = fmaxf(fminf(g.w, p.w) - fmaxf(g.y, p.y), 0.0f);
                const float inter = wx * wy;
                const float uni   = (ga + ap) - inter;
                const float a = inter * __builtin_amdgcn_rcpf(uni);  // approx iou
                if (a > bv1)      { bv2 = bv1; bv1 = a; bi = m; }    // first-max-wins
                else if (a > bv2) { bv2 = a; }
            }
        }

        float exact_v;
        {
#pragma clang fp contract(off)
            // Ambiguous: a real runner-up within the rcp safety margin.
            const bool ambig = (bv2 > 0.0f) && ((bv1 - bv2) <= 2e-6f * bv1);
            if (ambig) {
                // Exact-div argmax, first-max-wins — replicates numpy bit-for-bit.
                float bv = -1.0f; int nbi = 0;
                for (int m = 0; m < M_GT; ++m) {
                    const float4 g  = gt4[m];
                    const float  ga = (g.z - g.x) * (g.w - g.y);
                    const float wx = fmaxf(fminf(g.z, p.z) - fmaxf(g.x, p.x), 0.0f);
                    const float wy = fmaxf(fminf(g.w, p.w) - fmaxf(g.y, p.y), 0.0f);
                    const float inter = wx * wy;
                    const float iou = inter / ((ga + ap) - inter);
                    if (iou > bv) { bv = iou; nbi = m; }
                }
                bi = nbi;
            }
            // One exact IEEE div: matched_val of the winner (for the 0.5 test).
            const float4 g  = gt4[bi];
            const float  ga = (g.z - g.x) * (g.w - g.y);
            const float wx = fmaxf(fminf(g.z, p.z) - fmaxf(g.x, p.x), 0.0f);
            const float wy = fmaxf(fminf(g.w, p.w) - fmaxf(g.y, p.y), 0.0f);
            const float inter = wx * wy;
            exact_v = inter / ((ga + ap) - inter);
        }

        const int match = (exact_v < 0.5f) ? -1 : bi;  // FG==BG==0.5: BETWEEN dead

        // ---- BoxCoder.encode against matched (clamped) gt ----
        const float4 mg = gt4[match < 0 ? 0 : match];
        const float aw = p.z - p.x;
        const float ah = p.w - p.y;
        const float ax = p.x + 0.5f * aw;
        const float ay = p.y + 0.5f * ah;
        const float gw = fmaxf(mg.z - mg.x, 1.0f);
        const float gh = fmaxf(mg.w - mg.y, 1.0f);
        const float gx = mg.x + 0.5f * gw;
        const float gy = mg.y + 0.5f * gh;

        float4 tgt;
        tgt.x = ((gx - ax) / aw) / 0.1f;
        tgt.y = ((gy - ay) / ah) / 0.1f;
        tgt.z = logf(gw / aw) / 0.2f;
        tgt.w = logf(gh / ah) / 0.2f;

        // ---- BoxCoder.decode for predicted deltas ----
        const float4 d = reinterpret_cast<const float4*>(pdel)[pi];
        const float sx = d.x * 0.1f;
        const float sy = d.y * 0.1f;
        const float sw = d.z * 0.2f;
        const float sh = d.w * 0.2f;
        const float cx = ax + sx * aw;
        const float cy = ay + sy * ah;
        const float w2 = expf(sw) * aw;
        const float h2 = expf(sh) * ah;

        float4 dec;
        dec.x = cx - 0.5f * w2;
        dec.y = cy - 0.5f * h2;
        dec.z = cx + 0.5f * w2;
        dec.w = cy + 0.5f * h2;

        float4* pout4 = reinterpret_cast<float4*>(pout);
        const long BN = (long)B_IMGS * N_PROP;
        pout4[pi] = dec;                        // decoded
        pout4[BN + pi] = tgt;                   // targets
        pout[2 * BN * 4 + pi] = (float)match;   // matches as f32
    }
}

extern "C" void kernel_launch(void* const* d_in, const int* in_sizes, int n_in,
                              void* d_out, int out_size, void* d_ws, size_t ws_size,
                              hipStream_t stream) {
    const float* proposals = (const float*)d_in[0];
    const float* gt        = (const float*)d_in[1];
    const float* deltas    = (const float*)d_in[2];
    float* out = (float*)d_out;

    dim3 block(256);
    dim3 grid((N_PROP + 255) / 256, B_IMGS);
    roihead_kernel<<<grid, block, 0, stream>>>(proposals, gt, deltas, out);
}

// Round 9
// 86.814 us; speedup vs baseline: 1.8289x; 1.8289x over previous
//
#include <hip/hip_runtime.h>

// Problem constants (from setup_inputs): B=4, N=100000, M=64
#define B_IMGS 4
#define N_PROP 100000
#define M_GT   64

// Output layout (flat f32): decoded[B*N*4] | targets[B*N*4] | matches[B*N]
//
// R9: VALU-bound per R8 counters (VALUBusy 79%, ~64 lane-ops/pair). Cut to
// ~20 ops/pair:
//  - gt boxes via wave-uniform s_load (scalar cache), gt areas via LDS
//    ds_read_b32 (off the VALU pipe) — no SGPR-pair VALU movs.
//  - packed-key argmax: IoU>=0 so float bits are order-monotonic.
//    key = (bits(a) & ~63) | (63-m): v_and_or_b32 + v_max_u32 replaces
//    cmp+cndmask chains; first-max-wins preserved (equal-trunc ties pick
//    smaller m AND trigger the exact fallback).
//  - ambiguity margin 1e-5 covers rcp err (2.4e-7) + 6-LSB trunc (3.8e-6).
// Rare ambiguous lanes rerun the exact IEEE-div argmax (numpy bit-exact);
// one exact div per proposal recovers matched_val for the 0.5 threshold.

__global__ __launch_bounds__(256) void roihead_kernel(
    const float* __restrict__ proposals,  // [B,N,4]
    const float* __restrict__ gt,         // [B,M,4]
    const float* __restrict__ deltas,     // [B,N,4]
    float* __restrict__ out)
{
    __shared__ float ga_s[M_GT];

    const int b   = blockIdx.y;
    const int tid = threadIdx.x;
    const float4* __restrict__ gt4 = reinterpret_cast<const float4*>(gt) + b * M_GT;

    if (tid < M_GT) {
        const float4 g = gt4[tid];
        ga_s[tid] = (g.z - g.x) * (g.w - g.y);  // numpy op order
    }
    __syncthreads();

    const int n = blockIdx.x * blockDim.x + tid;
    if (n >= N_PROP) return;

    const long pi = (long)b * N_PROP + n;
    const float4 p = reinterpret_cast<const float4*>(proposals)[pi];

    unsigned k1 = 0u, k2 = 0u;  // top-2 packed keys: trunc(bits(a)) | (63-m)
    float ap;
    {
#pragma clang fp contract(off)
        ap = (p.z - p.x) * (p.w - p.y);
#pragma unroll 8
        for (int m = 0; m < M_GT; ++m) {
            const float4 g  = gt4[m];   // wave-uniform -> s_load (scalar cache)
            const float  ga = ga_s[m];  // ds_read_b32, off the VALU pipe
            const float wx = fmaxf(fminf(g.z, p.z) - fmaxf(g.x, p.x), 0.0f);
            const float wy = fmaxf(fminf(g.w, p.w) - fmaxf(g.y, p.y), 0.0f);
            const float inter = wx * wy;
            const float uni   = (ga + ap) - inter;
            const float a = inter * __builtin_amdgcn_rcpf(uni);  // approx iou >= 0
            const unsigned key =
                (__float_as_uint(a) & 0xFFFFFFC0u) | (unsigned)(63 - m);
            const unsigned t = k1 < key ? k1 : key;  // v_min_u32 (old k1)
            k1 = k1 > key ? k1 : key;                // v_max_u32
            k2 = k2 > t   ? k2 : t;                  // v_max_u32
        }
    }

    int bi = 63 - (int)(k1 & 63u);
    const float f1 = __uint_as_float(k1 & 0xFFFFFFC0u);
    const float f2 = __uint_as_float(k2 & 0xFFFFFFC0u);

    float exact_v;
    {
#pragma clang fp contract(off)
        // Ambiguous: a real runner-up within the (rcp + truncation) margin.
        const bool ambig = (f2 > 0.0f) && ((f1 - f2) <= 1e-5f * f1);
        if (ambig) {
            // Exact-div argmax, first-max-wins — replicates numpy bit-for-bit.
            float bv = -1.0f; int nbi = 0;
            for (int m = 0; m < M_GT; ++m) {
                const float4 g = gt4[m];
                const float wx = fmaxf(fminf(g.z, p.z) - fmaxf(g.x, p.x), 0.0f);
                const float wy = fmaxf(fminf(g.w, p.w) - fmaxf(g.y, p.y), 0.0f);
                const float inter = wx * wy;
                const float iou = inter / ((ga_s[m] + ap) - inter);
                if (iou > bv) { bv = iou; nbi = m; }
            }
            bi = nbi;
        }
        // One exact IEEE div: matched_val of the winner (for the 0.5 test).
        const float4 g = gt4[bi];
        const float wx = fmaxf(fminf(g.z, p.z) - fmaxf(g.x, p.x), 0.0f);
        const float wy = fmaxf(fminf(g.w, p.w) - fmaxf(g.y, p.y), 0.0f);
        const float inter = wx * wy;
        exact_v = inter / ((ga_s[bi] + ap) - inter);
    }

    const int match = (exact_v < 0.5f) ? -1 : bi;  // FG==BG==0.5: BETWEEN dead

    // ---- BoxCoder.encode against matched (clamped) gt ----
    const float4 mg = gt4[match < 0 ? 0 : match];
    const float aw = p.z - p.x;
    const float ah = p.w - p.y;
    const float ax = p.x + 0.5f * aw;
    const float ay = p.y + 0.5f * ah;
    const float gw = fmaxf(mg.z - mg.x, 1.0f);
    const float gh = fmaxf(mg.w - mg.y, 1.0f);
    const float gx = mg.x + 0.5f * gw;
    const float gy = mg.y + 0.5f * gh;

    float4 tgt;
    tgt.x = ((gx - ax) / aw) / 0.1f;
    tgt.y = ((gy - ay) / ah) / 0.1f;
    tgt.z = logf(gw / aw) / 0.2f;
    tgt.w = logf(gh / ah) / 0.2f;

    // ---- BoxCoder.decode for predicted deltas ----
    const float4 d = reinterpret_cast<const float4*>(deltas)[pi];
    const float sx = d.x * 0.1f;
    const float sy = d.y * 0.1f;
    const float sw = d.z * 0.2f;
    const float sh = d.w * 0.2f;
    const float cx = ax + sx * aw;
    const float cy = ay + sy * ah;
    const float w2 = expf(sw) * aw;
    const float h2 = expf(sh) * ah;

    float4 dec;
    dec.x = cx - 0.5f * w2;
    dec.y = cy - 0.5f * h2;
    dec.z = cx + 0.5f * w2;
    dec.w = cy + 0.5f * h2;

    float4* out4 = reinterpret_cast<float4*>(out);
    const long BN = (long)B_IMGS * N_PROP;
    out4[pi] = dec;                       // decoded
    out4[BN + pi] = tgt;                  // targets
    out[2 * BN * 4 + pi] = (float)match;  // matches as f32
}

extern "C" void kernel_launch(void* const* d_in, const int* in_sizes, int n_in,
                              void* d_out, int out_size, void* d_ws, size_t ws_size,
                              hipStream_t stream) {
    const float* proposals = (const float*)d_in[0];
    const float* gt        = (const float*)d_in[1];
    const float* deltas    = (const float*)d_in[2];
    float* out = (float*)d_out;

    dim3 block(256);
    dim3 grid((N_PROP + 255) / 256, B_IMGS);
    roihead_kernel<<<grid, block, 0, stream>>>(proposals, gt, deltas, out);
}